// Round 17
// baseline (199.421 us; speedup 1.0000x reference)
//
#include <hip/hip_runtime.h>
#include <hip/hip_bf16.h>
#include <stdint.h>
#include <stddef.h>

typedef __bf16 bf16_t;
typedef __bf16 bf16x8 __attribute__((ext_vector_type(8)));
typedef float floatx4 __attribute__((ext_vector_type(4)));

#define DIM 512
#define SEQ 4096
#define BATCH 8

static __device__ __forceinline__ floatx4 mfma_bf16(bf16x8 a, bf16x8 b, floatx4 c) {
  return __builtin_amdgcn_mfma_f32_16x16x32_bf16(a, b, c, 0, 0, 0);
}

typedef __attribute__((address_space(1))) const void* gas_ptr;
typedef __attribute__((address_space(3))) void* las_ptr;
static __device__ __forceinline__ void gll16(const void* g, void* l) {
  __builtin_amdgcn_global_load_lds((gas_ptr)g, (las_ptr)l, 16, 0, 0);
}

// ---------------- K0: fp32 -> bf16, w_qkv (blocks 0..383) and x (blocks 384..8575) ----------------
__global__ __launch_bounds__(256) void k_cvt2(const float* __restrict__ w, bf16_t* __restrict__ wb,
                                              const float* __restrict__ x, bf16_t* __restrict__ xb) {
  const float* src;
  bf16_t* dst;
  int blk = blockIdx.x;
  if (blk < 384) { src = w; dst = wb; }
  else           { src = x; dst = xb; blk -= 384; }
  int i = (blk * 256 + threadIdx.x) * 8;
  float4 a = *(const float4*)&src[i];
  float4 b = *(const float4*)&src[i + 4];
  bf16x8 o;
  o[0] = (bf16_t)a.x; o[1] = (bf16_t)a.y; o[2] = (bf16_t)a.z; o[3] = (bf16_t)a.w;
  o[4] = (bf16_t)b.x; o[5] = (bf16_t)b.y; o[6] = (bf16_t)b.z; o[7] = (bf16_t)b.w;
  *(bf16x8*)&dst[i] = o;
}

// ---------------- K1: qkv GEMM, 256x256, 8 waves, BK=64, dbuf, 4-phase (r16 race FIXED) ----------------
// Phase 0: stage A0(t+1) -> vmcnt(2) -> barrier -> THEN ds_read (r16 bug: reads were before the gate).
// Phases 1-3: read at top (tile t resident), stage half-tile, barrier, MFMA, barrier.
__global__ __launch_bounds__(512, 2) void k_qkv(const bf16_t* __restrict__ Xb,
                                                const bf16_t* __restrict__ Wb,
                                                bf16_t* __restrict__ qs,
                                                bf16_t* __restrict__ ek,
                                                bf16_t* __restrict__ vb,
                                                float* __restrict__ S) {
  __shared__ __align__(16) bf16_t As[2][256 * 64];  // 2 x 32 KB
  __shared__ __align__(16) bf16_t Bs[2][256 * 64];  // 2 x 32 KB
  const int tid = threadIdx.x;
  const int lane = tid & 63;
  const int w = tid >> 6;
  const int wr = w >> 2, wc = w & 3;   // wave tile 128 x 64
  const int l15 = lane & 15, l4 = lane >> 4;
  const int bid = blockIdx.x;
  const int xcd = bid & 7, local = bid >> 3;
  const int m0 = (xcd * 16 + local / 6) * 256;
  const int n0 = (local % 6) * 256;

  int sr[4], su[4];
#pragma unroll
  for (int i = 0; i < 4; ++i) {
    int s = tid + i * 512;
    sr[i] = s >> 3;
    su[i] = ((s & 7) ^ (sr[i] & 7)) << 3;
  }

  floatx4 acc[8][4];
#pragma unroll
  for (int i = 0; i < 8; ++i)
#pragma unroll
    for (int j = 0; j < 4; ++j) acc[i][j] = (floatx4){0.f, 0.f, 0.f, 0.f};

  // prologue: stage tile 0 into buf 0
#pragma unroll
  for (int i = 0; i < 4; ++i) {
    int s = tid + i * 512;
    gll16(Xb + (size_t)(m0 + sr[i]) * DIM + su[i], &As[0][s * 8]);
  }
#pragma unroll
  for (int i = 0; i < 4; ++i) {
    int s = tid + i * 512;
    gll16(Wb + (size_t)(n0 + sr[i]) * DIM + su[i], &Bs[0][s * 8]);
  }

  for (int t = 0; t < 8; ++t) {
    const int cur = t & 1;
    const bf16_t* Asc = &As[cur][0];
    const bf16_t* Bsc = &Bs[cur][0];
    bf16_t* Asn = &As[cur ^ 1][0];
    bf16_t* Bsn = &Bs[cur ^ 1][0];
    const int kt = (t + 1) * 64;
    bf16x8 af[4], bfr[4];

    // ---------- phase 0: gate, then kk=0 f=0..3 ----------
    if (t < 7) {
#pragma unroll
      for (int i = 0; i < 2; ++i) {
        int s = tid + i * 512;
        gll16(Xb + (size_t)(m0 + sr[i]) * DIM + kt + su[i], Asn + s * 8);
      }
      asm volatile("s_waitcnt vmcnt(2)" ::: "memory");  // tile t's 8 loads landed; 2 new in flight
    } else {
      asm volatile("s_waitcnt vmcnt(0)" ::: "memory");
    }
    __builtin_amdgcn_sched_barrier(0);
    __builtin_amdgcn_s_barrier();            // tile t visible to all waves
#pragma unroll
    for (int f = 0; f < 4; ++f) {
      int ar = wr * 128 + f * 16 + l15;
      af[f] = *(const bf16x8*)(Asc + ar * 64 + (l4 ^ (ar & 7)) * 8);
    }
#pragma unroll
    for (int f = 0; f < 4; ++f) {
      int br = wc * 64 + f * 16 + l15;
      bfr[f] = *(const bf16x8*)(Bsc + br * 64 + (l4 ^ (br & 7)) * 8);
    }
    __builtin_amdgcn_s_setprio(1);
#pragma unroll
    for (int f = 0; f < 4; ++f)
#pragma unroll
      for (int j = 0; j < 4; ++j)
        acc[f][j] = mfma_bf16(af[f], bfr[j], acc[f][j]);
    __builtin_amdgcn_s_setprio(0);
    __builtin_amdgcn_sched_barrier(0);
    __builtin_amdgcn_s_barrier();

    // ---------- phase 1: kk=0 f=4..7 ; stage A-half1(t+1) ----------
#pragma unroll
    for (int f = 0; f < 4; ++f) {
      int ar = wr * 128 + (f + 4) * 16 + l15;
      af[f] = *(const bf16x8*)(Asc + ar * 64 + (l4 ^ (ar & 7)) * 8);
    }
    if (t < 7) {
#pragma unroll
      for (int i = 2; i < 4; ++i) {
        int s = tid + i * 512;
        gll16(Xb + (size_t)(m0 + sr[i]) * DIM + kt + su[i], Asn + s * 8);
      }
    }
    __builtin_amdgcn_sched_barrier(0);
    __builtin_amdgcn_s_barrier();
    __builtin_amdgcn_s_setprio(1);
#pragma unroll
    for (int f = 0; f < 4; ++f)
#pragma unroll
      for (int j = 0; j < 4; ++j)
        acc[f + 4][j] = mfma_bf16(af[f], bfr[j], acc[f + 4][j]);
    __builtin_amdgcn_s_setprio(0);
    __builtin_amdgcn_sched_barrier(0);
    __builtin_amdgcn_s_barrier();

    // ---------- phase 2: kk=1 f=0..3 ; stage B-half0(t+1) ----------
#pragma unroll
    for (int f = 0; f < 4; ++f) {
      int ar = wr * 128 + f * 16 + l15;
      af[f] = *(const bf16x8*)(Asc + ar * 64 + ((4 + l4) ^ (ar & 7)) * 8);
    }
#pragma unroll
    for (int f = 0; f < 4; ++f) {
      int br = wc * 64 + f * 16 + l15;
      bfr[f] = *(const bf16x8*)(Bsc + br * 64 + ((4 + l4) ^ (br & 7)) * 8);
    }
    if (t < 7) {
#pragma unroll
      for (int i = 0; i < 2; ++i) {
        int s = tid + i * 512;
        gll16(Wb + (size_t)(n0 + sr[i]) * DIM + kt + su[i], Bsn + s * 8);
      }
    }
    __builtin_amdgcn_sched_barrier(0);
    __builtin_amdgcn_s_barrier();
    __builtin_amdgcn_s_setprio(1);
#pragma unroll
    for (int f = 0; f < 4; ++f)
#pragma unroll
      for (int j = 0; j < 4; ++j)
        acc[f][j] = mfma_bf16(af[f], bfr[j], acc[f][j]);
    __builtin_amdgcn_s_setprio(0);
    __builtin_amdgcn_sched_barrier(0);
    __builtin_amdgcn_s_barrier();

    // ---------- phase 3: kk=1 f=4..7 ; stage B-half1(t+1) ----------
#pragma unroll
    for (int f = 0; f < 4; ++f) {
      int ar = wr * 128 + (f + 4) * 16 + l15;
      af[f] = *(const bf16x8*)(Asc + ar * 64 + ((4 + l4) ^ (ar & 7)) * 8);
    }
    if (t < 7) {
#pragma unroll
      for (int i = 2; i < 4; ++i) {
        int s = tid + i * 512;
        gll16(Wb + (size_t)(n0 + sr[i]) * DIM + kt + su[i], Bsn + s * 8);
      }
    }
    __builtin_amdgcn_sched_barrier(0);
    __builtin_amdgcn_s_barrier();
    __builtin_amdgcn_s_setprio(1);
#pragma unroll
    for (int f = 0; f < 4; ++f)
#pragma unroll
      for (int j = 0; j < 4; ++j)
        acc[f + 4][j] = mfma_bf16(af[f], bfr[j], acc[f + 4][j]);
    __builtin_amdgcn_s_setprio(0);
    __builtin_amdgcn_sched_barrier(0);
    __builtin_amdgcn_s_barrier();   // end of tile: all reads of buf[cur] done before t+1 overwrites it
  }

  const int colbase = n0 + wc * 64;
  if (n0 < 512) {
#pragma unroll
    for (int fm = 0; fm < 8; ++fm) {
#pragma unroll
      for (int r = 0; r < 4; ++r) {
        float v0 = acc[fm][0][r], v1 = acc[fm][1][r], v2 = acc[fm][2][r], v3 = acc[fm][3][r];
        float mx = fmaxf(fmaxf(v0, v1), fmaxf(v2, v3));
        mx = fmaxf(mx, __shfl_xor(mx, 1));
        mx = fmaxf(mx, __shfl_xor(mx, 2));
        mx = fmaxf(mx, __shfl_xor(mx, 4));
        mx = fmaxf(mx, __shfl_xor(mx, 8));
        float e0 = __expf(v0 - mx), e1 = __expf(v1 - mx), e2 = __expf(v2 - mx), e3 = __expf(v3 - mx);
        float s = e0 + e1 + e2 + e3;
        s += __shfl_xor(s, 1); s += __shfl_xor(s, 2); s += __shfl_xor(s, 4); s += __shfl_xor(s, 8);
        float inv = 0.125f / s;
        int m = m0 + wr * 128 + fm * 16 + l4 * 4 + r;
        bf16_t* rowp = qs + (size_t)m * DIM + colbase;
        rowp[l15]      = (bf16_t)(e0 * inv);
        rowp[16 + l15] = (bf16_t)(e1 * inv);
        rowp[32 + l15] = (bf16_t)(e2 * inv);
        rowp[48 + l15] = (bf16_t)(e3 * inv);
      }
    }
  } else if (n0 < 1024) {
    const int cb = colbase - 512;
    float c0 = 0.f, c1 = 0.f, c2 = 0.f, c3 = 0.f;
#pragma unroll
    for (int fm = 0; fm < 8; ++fm) {
#pragma unroll
      for (int r = 0; r < 4; ++r) {
        int m = m0 + wr * 128 + fm * 16 + l4 * 4 + r;
        bf16_t* rowp = ek + (size_t)m * DIM + cb;
        float e0 = __expf(acc[fm][0][r]);
        float e1 = __expf(acc[fm][1][r]);
        float e2 = __expf(acc[fm][2][r]);
        float e3 = __expf(acc[fm][3][r]);
        rowp[l15]      = (bf16_t)e0;
        rowp[16 + l15] = (bf16_t)e1;
        rowp[32 + l15] = (bf16_t)e2;
        rowp[48 + l15] = (bf16_t)e3;
        c0 += e0; c1 += e1; c2 += e2; c3 += e3;
      }
    }
    c0 += __shfl_xor(c0, 16); c0 += __shfl_xor(c0, 32);
    c1 += __shfl_xor(c1, 16); c1 += __shfl_xor(c1, 32);
    c2 += __shfl_xor(c2, 16); c2 += __shfl_xor(c2, 32);
    c3 += __shfl_xor(c3, 16); c3 += __shfl_xor(c3, 32);
    if (lane < 16) {
      int b = m0 >> 12;
      atomicAdd(&S[b * 512 + cb + lane],      c0);
      atomicAdd(&S[b * 512 + cb + 16 + lane], c1);
      atomicAdd(&S[b * 512 + cb + 32 + lane], c2);
      atomicAdd(&S[b * 512 + cb + 48 + lane], c3);
    }
  } else {
    const int cb = colbase - 1024;
#pragma unroll
    for (int fm = 0; fm < 8; ++fm) {
#pragma unroll
      for (int r = 0; r < 4; ++r) {
        int m = m0 + wr * 128 + fm * 16 + l4 * 4 + r;
        bf16_t* rowp = vb + (size_t)m * DIM + cb;
        rowp[l15]      = (bf16_t)acc[fm][0][r];
        rowp[16 + l15] = (bf16_t)acc[fm][1][r];
        rowp[32 + l15] = (bf16_t)acc[fm][2][r];
        rowp[48 + l15] = (bf16_t)acc[fm][3][r];
      }
    }
  }
}

// ---------------- K2: ctxpart = ek_chunk^T @ v_chunk — coalesced staging + XOR-swizzled transpose ----------------
#define TP 136
__global__ __launch_bounds__(256) void k_ctx(const bf16_t* __restrict__ ek,
                                             const bf16_t* __restrict__ vb,
                                             float* __restrict__ ctxpart) {
  __shared__ __align__(16) bf16_t ekT[64 * TP];
  __shared__ __align__(16) bf16_t vT[64 * TP];
  __shared__ float red[4096];
  const int tid = threadIdx.x;
  const int lane = tid & 63, wid = tid >> 6;
  const int l15 = lane & 15, l4 = lane >> 4;
  const int bh = blockIdx.x, chunk = blockIdx.y;
  const int b = bh >> 3, h = bh & 7;
  const int base = b * SEQ + chunk * 512;

  floatx4 acc[4][4];
#pragma unroll
  for (int i = 0; i < 4; ++i)
#pragma unroll
    for (int j = 0; j < 4; ++j) acc[i][j] = (floatx4){0.f, 0.f, 0.f, 0.f};

  for (int nt = 0; nt < 4; ++nt) {
    const int n0 = base + nt * 128;
    if (nt) __syncthreads();
#pragma unroll
    for (int i = 0; i < 4; ++i) {
      int q = tid + i * 256;
      int n = q >> 3;
      int u = q & 7;
      bf16x8 vk = *(const bf16x8*)&ek[(size_t)(n0 + n) * DIM + h * 64 + u * 8];
      bf16x8 vv = *(const bf16x8*)&vb[(size_t)(n0 + n) * DIM + h * 64 + u * 8];
      int ncol = n ^ (u << 3);
#pragma unroll
      for (int j = 0; j < 8; ++j) {
        int c = u * 8 + j;
        ekT[c * TP + ncol] = vk[j];
        vT [c * TP + ncol] = vv[j];
      }
    }
    __syncthreads();
    const int nb = wid * 32;
    bf16x8 af[4], bfr[4];
#pragma unroll
    for (int f = 0; f < 4; ++f) {
      int c = f * 16 + l15;
      int colstart = (nb + l4 * 8) ^ (((c >> 3) & 7) << 3);
      af[f]  = *(const bf16x8*)&ekT[c * TP + colstart];
      bfr[f] = *(const bf16x8*)&vT [c * TP + colstart];
    }
#pragma unroll
    for (int i = 0; i < 4; ++i)
#pragma unroll
      for (int j = 0; j < 4; ++j)
        acc[i][j] = mfma_bf16(af[i], bfr[j], acc[i][j]);
  }

  __syncthreads();
  for (int w = 0; w < 4; ++w) {
    if (wid == w) {
#pragma unroll
      for (int fm = 0; fm < 4; ++fm)
#pragma unroll
        for (int fn = 0; fn < 4; ++fn)
#pragma unroll
          for (int r = 0; r < 4; ++r) {
            int d = fm * 16 + l4 * 4 + r;
            int e = fn * 16 + l15;
            if (w == 0) red[d * 64 + e] = acc[fm][fn][r];
            else        red[d * 64 + e] += acc[fm][fn][r];
          }
    }
    __syncthreads();
  }
  float* dst = ctxpart + ((size_t)bh * 8 + chunk) * 4096;
#pragma unroll
  for (int i = 0; i < 4; ++i) {
    int q = tid + i * 256;
    *(float4*)&dst[q * 4] = *(const float4*)&red[q * 4];
  }
}

// ---------------- K3: reduce partials, /S, then Mt[b][dcol][h*64+d] ----------------
__global__ __launch_bounds__(256) void k_mt(const float* __restrict__ ctxpart,
                                            const float* __restrict__ S,
                                            const float* __restrict__ w_out,
                                            bf16_t* __restrict__ Mt) {
  __shared__ float cs[4096];
  const int tid = threadIdx.x;
  const int bh = blockIdx.x;
  const int b = bh >> 3, h = bh & 7;
#pragma unroll
  for (int i = 0; i < 16; ++i) {
    int idx = tid + i * 256;
    float s = 0.f;
#pragma unroll
    for (int p = 0; p < 8; ++p) s += ctxpart[((size_t)bh * 8 + p) * 4096 + idx];
    cs[idx] = s / S[b * 512 + h * 64 + (idx >> 6)];
  }
  __syncthreads();
  for (int half = 0; half < 2; ++half) {
    const int dcol = half * 256 + tid;
    float a[64];
#pragma unroll
    for (int d = 0; d < 64; ++d) a[d] = 0.f;
    for (int e = 0; e < 64; ++e) {
      float we = w_out[(size_t)dcol * 512 + h * 64 + e];
#pragma unroll
      for (int d = 0; d < 64; ++d) a[d] += cs[d * 64 + e] * we;
    }
    bf16_t* dst = Mt + ((size_t)b * 512 + dcol) * 512 + h * 64;
#pragma unroll
    for (int g = 0; g < 8; ++g) {
      bf16x8 o;
#pragma unroll
      for (int j = 0; j < 8; ++j) o[j] = (bf16_t)a[g * 8 + j];
      *(bf16x8*)&dst[g * 8] = o;
    }
  }
}

// ---------------- K4: out = LN(qs[b] @ Mt[b]) fused, pipelined, XCD swizzle (batch == xcd) ----------------
__global__ __launch_bounds__(512, 2) void k_out(const bf16_t* __restrict__ qs,
                                                const bf16_t* __restrict__ Mt,
                                                const float* __restrict__ gamma,
                                                float* __restrict__ out) {
  __shared__ __align__(16) bf16_t As[2][128 * 64];  // 2 x 16 KB
  __shared__ __align__(16) bf16_t Bs[512 * 64];     // 64 KB
  __shared__ float redS[128 * 4];
  __shared__ float redQ[128 * 4];
  const int tid = threadIdx.x;
  const int lane = tid & 63;
  const int w = tid >> 6;
  const int wr = w >> 2, wc = w & 3;
  const int l15 = lane & 15, l4 = lane >> 4;
  const int bid = blockIdx.x;
  const int sbid = (bid & 7) * 32 + (bid >> 3);
  const int m0 = sbid * 128;
  const bf16_t* Bp = Mt + (size_t)(sbid >> 5) * 512 * 512;

  int aR[2], aU[2];
#pragma unroll
  for (int i = 0; i < 2; ++i) {
    int s = tid + i * 512;
    aR[i] = s >> 3;
    aU[i] = ((s & 7) ^ (aR[i] & 7)) << 3;
  }
  int bR[8], bU[8];
#pragma unroll
  for (int i = 0; i < 8; ++i) {
    int s = tid + i * 512;
    bR[i] = s >> 3;
    bU[i] = ((s & 7) ^ (bR[i] & 7)) << 3;
  }

  floatx4 acc[4][8];
#pragma unroll
  for (int i = 0; i < 4; ++i)
#pragma unroll
    for (int j = 0; j < 8; ++j) acc[i][j] = (floatx4){0.f, 0.f, 0.f, 0.f};

  bf16x8 breg[8];
#pragma unroll
  for (int i = 0; i < 2; ++i)
    gll16(qs + (size_t)(m0 + aR[i]) * 512 + aU[i], &As[0][(tid + i * 512) * 8]);
#pragma unroll
  for (int i = 0; i < 8; ++i)
    breg[i] = *(const bf16x8*)(Bp + (size_t)bR[i] * 512 + bU[i]);
  asm volatile("s_waitcnt vmcnt(0)" ::: "memory");
#pragma unroll
  for (int i = 0; i < 8; ++i)
    *(bf16x8*)(&Bs[(tid + i * 512) * 8]) = breg[i];
  asm volatile("s_waitcnt lgkmcnt(0)" ::: "memory");
  __builtin_amdgcn_s_barrier();

  for (int t = 0; t < 8; ++t) {
    const int cur = t & 1;
    if (t < 7) {
      const int kt = (t + 1) * 64;
#pragma unroll
      for (int i = 0; i < 2; ++i)
        gll16(qs + (size_t)(m0 + aR[i]) * 512 + kt + aU[i], &As[cur ^ 1][(tid + i * 512) * 8]);
#pragma unroll
      for (int i = 0; i < 8; ++i)
        breg[i] = *(const bf16x8*)(Bp + (size_t)bR[i] * 512 + kt + bU[i]);
    }
    __builtin_amdgcn_s_setprio(1);
#pragma unroll
    for (int kk = 0; kk < 2; ++kk) {
      bf16x8 af[4], bfr[8];
#pragma unroll
      for (int f = 0; f < 4; ++f) {
        int ar = wr * 64 + f * 16 + l15;
        int ua = (kk * 4 + l4) ^ (ar & 7);
        af[f] = *(const bf16x8*)(&As[cur][ar * 64 + ua * 8]);
      }
#pragma unroll
      for (int f = 0; f < 8; ++f) {
        int br = wc * 128 + f * 16 + l15;
        int ub = (kk * 4 + l4) ^ (br & 7);
        bfr[f] = *(const bf16x8*)(&Bs[br * 64 + ub * 8]);
      }
#pragma unroll
      for (int i = 0; i < 4; ++i)
#pragma unroll
        for (int j = 0; j < 8; ++j)
          acc[i][j] = mfma_bf16(af[i], bfr[j], acc[i][j]);
    }
    __builtin_amdgcn_s_setprio(0);
    __builtin_amdgcn_sched_barrier(0);
    __builtin_amdgcn_s_barrier();
    if (t < 7) {
      asm volatile("s_waitcnt vmcnt(0)" ::: "memory");
#pragma unroll
      for (int i = 0; i < 8; ++i)
        *(bf16x8*)(&Bs[(tid + i * 512) * 8]) = breg[i];
      asm volatile("s_waitcnt lgkmcnt(0)" ::: "memory");
      __builtin_amdgcn_s_barrier();
    }
  }

#pragma unroll
  for (int fm = 0; fm < 4; ++fm) {
#pragma unroll
    for (int r = 0; r < 4; ++r) {
      float s = 0.f, q = 0.f;
#pragma unroll
      for (int fn = 0; fn < 8; ++fn) {
        float v = acc[fm][fn][r];
        s += v; q += v * v;
      }
      s += __shfl_xor(s, 1); q += __shfl_xor(q, 1);
      s += __shfl_xor(s, 2); q += __shfl_xor(q, 2);
      s += __shfl_xor(s, 4); q += __shfl_xor(q, 4);
      s += __shfl_xor(s, 8); q += __shfl_xor(q, 8);
      if (l15 == 0) {
        int rl = wr * 64 + fm * 16 + l4 * 4 + r;
        redS[rl * 4 + wc] = s;
        redQ[rl * 4 + wc] = q;
      }
    }
  }
  __syncthreads();
  float gm[8];
#pragma unroll
  for (int fn = 0; fn < 8; ++fn) gm[fn] = gamma[wc * 128 + fn * 16 + l15];
#pragma unroll
  for (int fm = 0; fm < 4; ++fm) {
#pragma unroll
    for (int r = 0; r < 4; ++r) {
      int rl = wr * 64 + fm * 16 + l4 * 4 + r;
      float4 sv = *(const float4*)&redS[rl * 4];
      float4 qv = *(const float4*)&redQ[rl * 4];
      float Sr = sv.x + sv.y + sv.z + sv.w;
      float Qr = qv.x + qv.y + qv.z + qv.w;
      float mean = Sr * (1.f / 512.f);
      float var = Qr * (1.f / 512.f) - mean * mean;
      float rstd = rsqrtf(var + 1e-5f);
      float* rowp = out + (size_t)(m0 + rl) * 512 + wc * 128 + l15;
#pragma unroll
      for (int fn = 0; fn < 8; ++fn)
        rowp[fn * 16] = (acc[fm][fn][r] - mean) * rstd * gm[fn];
    }
  }
}

extern "C" void kernel_launch(void* const* d_in, const int* in_sizes, int n_in,
                              void* d_out, int out_size, void* d_ws, size_t ws_size,
                              hipStream_t stream) {
  const float* x     = (const float*)d_in[0];
  const float* w_qkv = (const float*)d_in[1];
  const float* w_out = (const float*)d_in[2];
  const float* gamma = (const float*)d_in[3];
  float* out = (float*)d_out;
  char* ws = (char*)d_ws;

  bf16_t* qs      = (bf16_t*)(ws);                       // 33,554,432
  bf16_t* ek      = (bf16_t*)(ws + 33554432);            // 33,554,432
  bf16_t* vb      = (bf16_t*)(ws + 67108864);            // 33,554,432
  bf16_t* wqkvb   = (bf16_t*)(ws + 100663296);           //  1,572,864
  float*  S       = (float*)(ws + 102236160);            //     16,384
  bf16_t* Xb      = (bf16_t*)(ws + 102252544);           // 33,554,432 (dead after k_qkv)
  float*  ctxpart = (float*)(ws + 103301120);            //  8,388,608 (alias Xb tail, written AFTER Xb dead)
  bf16_t* Mt      = (bf16_t*)(ws + 111689728);           //  4,194,304 (alias Xb tail)

  hipMemsetAsync(S, 0, BATCH * 512 * sizeof(float), stream);

  k_cvt2<<<8576, 256, 0, stream>>>(w_qkv, wqkvb, x, Xb);

  k_qkv<<<768, 512, 0, stream>>>(Xb, wqkvb, qs, ek, vb, S);

  dim3 g2(64, 8);
  k_ctx<<<g2, 256, 0, stream>>>(ek, vb, ctxpart);

  k_mt<<<64, 256, 0, stream>>>(ctxpart, S, w_out, Mt);

  k_out<<<256, 512, 0, stream>>>(qs, Mt, gamma, out);
}

// Round 18
// 192.488 us; speedup vs baseline: 1.0360x; 1.0360x over previous
//
#include <hip/hip_runtime.h>
#include <hip/hip_bf16.h>
#include <stdint.h>
#include <stddef.h>

typedef __bf16 bf16_t;
typedef __bf16 bf16x8 __attribute__((ext_vector_type(8)));
typedef float floatx4 __attribute__((ext_vector_type(4)));

#define DIM 512
#define SEQ 4096
#define BATCH 8

static __device__ __forceinline__ floatx4 mfma_bf16(bf16x8 a, bf16x8 b, floatx4 c) {
  return __builtin_amdgcn_mfma_f32_16x16x32_bf16(a, b, c, 0, 0, 0);
}

typedef __attribute__((address_space(1))) const void* gas_ptr;
typedef __attribute__((address_space(3))) void* las_ptr;
static __device__ __forceinline__ void gll16(const void* g, void* l) {
  __builtin_amdgcn_global_load_lds((gas_ptr)g, (las_ptr)l, 16, 0, 0);
}

// ---------------- K0: fp32->bf16 (w: 0..383, x: 384..8575) + zero S (block 8576; S does NOT alias Xb) ----------------
__global__ __launch_bounds__(256) void k_cvt2(const float* __restrict__ w, bf16_t* __restrict__ wb,
                                              const float* __restrict__ x, bf16_t* __restrict__ xb,
                                              float* __restrict__ S) {
  int blk = blockIdx.x;
  if (blk == 8576) {
    float4 zv = {0.f, 0.f, 0.f, 0.f};
    ((float4*)S)[threadIdx.x * 4]     = zv;
    ((float4*)S)[threadIdx.x * 4 + 1] = zv;
    ((float4*)S)[threadIdx.x * 4 + 2] = zv;
    ((float4*)S)[threadIdx.x * 4 + 3] = zv;
    return;
  }
  const float* src;
  bf16_t* dst;
  if (blk < 384) { src = w; dst = wb; }
  else           { src = x; dst = xb; blk -= 384; }
  int i = (blk * 256 + threadIdx.x) * 8;
  float4 a = *(const float4*)&src[i];
  float4 b = *(const float4*)&src[i + 4];
  bf16x8 o;
  o[0] = (bf16_t)a.x; o[1] = (bf16_t)a.y; o[2] = (bf16_t)a.z; o[3] = (bf16_t)a.w;
  o[4] = (bf16_t)b.x; o[5] = (bf16_t)b.y; o[6] = (bf16_t)b.z; o[7] = (bf16_t)b.w;
  *(bf16x8*)&dst[i] = o;
}

// ---------------- K1: qkv GEMM, 256x256 tile, 8 waves, BK=64, dbuf + counted vmcnt(8) + XCD swizzle ----------------
// r11/r15-best config (79us, MfmaUtil 26%, FETCH 35MB, 0 conflicts). 4-phase split tested r17: null (-3%).
__global__ __launch_bounds__(512, 2) void k_qkv(const bf16_t* __restrict__ Xb,
                                                const bf16_t* __restrict__ Wb,
                                                bf16_t* __restrict__ qs,
                                                bf16_t* __restrict__ ek,
                                                bf16_t* __restrict__ vb,
                                                float* __restrict__ S) {
  __shared__ __align__(16) bf16_t As[2][256 * 64];  // 2 x 32 KB
  __shared__ __align__(16) bf16_t Bs[2][256 * 64];  // 2 x 32 KB
  const int tid = threadIdx.x;
  const int lane = tid & 63;
  const int w = tid >> 6;
  const int wr = w >> 2, wc = w & 3;   // wave tile 128 x 64
  const int l15 = lane & 15, l4 = lane >> 4;
  const int bid = blockIdx.x;
  const int xcd = bid & 7, local = bid >> 3;
  const int m0 = (xcd * 16 + local / 6) * 256;
  const int n0 = (local % 6) * 256;

  int sr[4], su[4];
#pragma unroll
  for (int i = 0; i < 4; ++i) {
    int s = tid + i * 512;
    sr[i] = s >> 3;
    su[i] = ((s & 7) ^ (sr[i] & 7)) << 3;
  }

  floatx4 acc[8][4];
#pragma unroll
  for (int i = 0; i < 8; ++i)
#pragma unroll
    for (int j = 0; j < 4; ++j) acc[i][j] = (floatx4){0.f, 0.f, 0.f, 0.f};

#pragma unroll
  for (int i = 0; i < 4; ++i) {
    int s = tid + i * 512;
    gll16(Xb + (size_t)(m0 + sr[i]) * DIM + su[i], &As[0][s * 8]);
    gll16(Wb + (size_t)(n0 + sr[i]) * DIM + su[i], &Bs[0][s * 8]);
  }

  for (int t = 0; t < 8; ++t) {
    const int cur = t & 1;
    if (t < 7) {
      const int kt = (t + 1) * 64;
#pragma unroll
      for (int i = 0; i < 4; ++i) {
        int s = tid + i * 512;
        gll16(Xb + (size_t)(m0 + sr[i]) * DIM + kt + su[i], &As[cur ^ 1][s * 8]);
        gll16(Wb + (size_t)(n0 + sr[i]) * DIM + kt + su[i], &Bs[cur ^ 1][s * 8]);
      }
      asm volatile("s_waitcnt vmcnt(8)" ::: "memory");
    } else {
      asm volatile("s_waitcnt vmcnt(0)" ::: "memory");
    }
    __builtin_amdgcn_s_barrier();
    __builtin_amdgcn_sched_barrier(0);
    __builtin_amdgcn_s_setprio(1);
#pragma unroll
    for (int kk = 0; kk < 2; ++kk) {
      bf16x8 af[8], bfr[4];
#pragma unroll
      for (int f = 0; f < 8; ++f) {
        int ar = wr * 128 + f * 16 + l15;
        int ua = (kk * 4 + l4) ^ (ar & 7);
        af[f] = *(const bf16x8*)(&As[cur][ar * 64 + ua * 8]);
      }
#pragma unroll
      for (int f = 0; f < 4; ++f) {
        int br = wc * 64 + f * 16 + l15;
        int ub = (kk * 4 + l4) ^ (br & 7);
        bfr[f] = *(const bf16x8*)(&Bs[cur][br * 64 + ub * 8]);
      }
#pragma unroll
      for (int i = 0; i < 8; ++i)
#pragma unroll
        for (int j = 0; j < 4; ++j)
          acc[i][j] = mfma_bf16(af[i], bfr[j], acc[i][j]);
    }
    __builtin_amdgcn_s_setprio(0);
    __builtin_amdgcn_sched_barrier(0);
    __builtin_amdgcn_s_barrier();
  }

  const int colbase = n0 + wc * 64;
  if (n0 < 512) {
#pragma unroll
    for (int fm = 0; fm < 8; ++fm) {
#pragma unroll
      for (int r = 0; r < 4; ++r) {
        float v0 = acc[fm][0][r], v1 = acc[fm][1][r], v2 = acc[fm][2][r], v3 = acc[fm][3][r];
        float mx = fmaxf(fmaxf(v0, v1), fmaxf(v2, v3));
        mx = fmaxf(mx, __shfl_xor(mx, 1));
        mx = fmaxf(mx, __shfl_xor(mx, 2));
        mx = fmaxf(mx, __shfl_xor(mx, 4));
        mx = fmaxf(mx, __shfl_xor(mx, 8));
        float e0 = __expf(v0 - mx), e1 = __expf(v1 - mx), e2 = __expf(v2 - mx), e3 = __expf(v3 - mx);
        float s = e0 + e1 + e2 + e3;
        s += __shfl_xor(s, 1); s += __shfl_xor(s, 2); s += __shfl_xor(s, 4); s += __shfl_xor(s, 8);
        float inv = 0.125f / s;
        int m = m0 + wr * 128 + fm * 16 + l4 * 4 + r;
        bf16_t* rowp = qs + (size_t)m * DIM + colbase;
        rowp[l15]      = (bf16_t)(e0 * inv);
        rowp[16 + l15] = (bf16_t)(e1 * inv);
        rowp[32 + l15] = (bf16_t)(e2 * inv);
        rowp[48 + l15] = (bf16_t)(e3 * inv);
      }
    }
  } else if (n0 < 1024) {
    const int cb = colbase - 512;
    float c0 = 0.f, c1 = 0.f, c2 = 0.f, c3 = 0.f;
#pragma unroll
    for (int fm = 0; fm < 8; ++fm) {
#pragma unroll
      for (int r = 0; r < 4; ++r) {
        int m = m0 + wr * 128 + fm * 16 + l4 * 4 + r;
        bf16_t* rowp = ek + (size_t)m * DIM + cb;
        float e0 = __expf(acc[fm][0][r]);
        float e1 = __expf(acc[fm][1][r]);
        float e2 = __expf(acc[fm][2][r]);
        float e3 = __expf(acc[fm][3][r]);
        rowp[l15]      = (bf16_t)e0;
        rowp[16 + l15] = (bf16_t)e1;
        rowp[32 + l15] = (bf16_t)e2;
        rowp[48 + l15] = (bf16_t)e3;
        c0 += e0; c1 += e1; c2 += e2; c3 += e3;
      }
    }
    c0 += __shfl_xor(c0, 16); c0 += __shfl_xor(c0, 32);
    c1 += __shfl_xor(c1, 16); c1 += __shfl_xor(c1, 32);
    c2 += __shfl_xor(c2, 16); c2 += __shfl_xor(c2, 32);
    c3 += __shfl_xor(c3, 16); c3 += __shfl_xor(c3, 32);
    if (lane < 16) {
      int b = m0 >> 12;
      atomicAdd(&S[b * 512 + cb + lane],      c0);
      atomicAdd(&S[b * 512 + cb + 16 + lane], c1);
      atomicAdd(&S[b * 512 + cb + 32 + lane], c2);
      atomicAdd(&S[b * 512 + cb + 48 + lane], c3);
    }
  } else {
    const int cb = colbase - 1024;
#pragma unroll
    for (int fm = 0; fm < 8; ++fm) {
#pragma unroll
      for (int r = 0; r < 4; ++r) {
        int m = m0 + wr * 128 + fm * 16 + l4 * 4 + r;
        bf16_t* rowp = vb + (size_t)m * DIM + cb;
        rowp[l15]      = (bf16_t)acc[fm][0][r];
        rowp[16 + l15] = (bf16_t)acc[fm][1][r];
        rowp[32 + l15] = (bf16_t)acc[fm][2][r];
        rowp[48 + l15] = (bf16_t)acc[fm][3][r];
      }
    }
  }
}

// ---------------- K2: ctxpart = ek_chunk^T @ v_chunk — coalesced staging + XOR-swizzled transpose ----------------
#define TP 136
__global__ __launch_bounds__(256) void k_ctx(const bf16_t* __restrict__ ek,
                                             const bf16_t* __restrict__ vb,
                                             float* __restrict__ ctxpart) {
  __shared__ __align__(16) bf16_t ekT[64 * TP];
  __shared__ __align__(16) bf16_t vT[64 * TP];
  __shared__ float red[4096];
  const int tid = threadIdx.x;
  const int lane = tid & 63, wid = tid >> 6;
  const int l15 = lane & 15, l4 = lane >> 4;
  const int bh = blockIdx.x, chunk = blockIdx.y;
  const int b = bh >> 3, h = bh & 7;
  const int base = b * SEQ + chunk * 512;

  floatx4 acc[4][4];
#pragma unroll
  for (int i = 0; i < 4; ++i)
#pragma unroll
    for (int j = 0; j < 4; ++j) acc[i][j] = (floatx4){0.f, 0.f, 0.f, 0.f};

  for (int nt = 0; nt < 4; ++nt) {
    const int n0 = base + nt * 128;
    if (nt) __syncthreads();
#pragma unroll
    for (int i = 0; i < 4; ++i) {
      int q = tid + i * 256;
      int n = q >> 3;
      int u = q & 7;
      bf16x8 vk = *(const bf16x8*)&ek[(size_t)(n0 + n) * DIM + h * 64 + u * 8];
      bf16x8 vv = *(const bf16x8*)&vb[(size_t)(n0 + n) * DIM + h * 64 + u * 8];
      int ncol = n ^ (u << 3);
#pragma unroll
      for (int j = 0; j < 8; ++j) {
        int c = u * 8 + j;
        ekT[c * TP + ncol] = vk[j];
        vT [c * TP + ncol] = vv[j];
      }
    }
    __syncthreads();
    const int nb = wid * 32;
    bf16x8 af[4], bfr[4];
#pragma unroll
    for (int f = 0; f < 4; ++f) {
      int c = f * 16 + l15;
      int colstart = (nb + l4 * 8) ^ (((c >> 3) & 7) << 3);
      af[f]  = *(const bf16x8*)&ekT[c * TP + colstart];
      bfr[f] = *(const bf16x8*)&vT [c * TP + colstart];
    }
#pragma unroll
    for (int i = 0; i < 4; ++i)
#pragma unroll
      for (int j = 0; j < 4; ++j)
        acc[i][j] = mfma_bf16(af[i], bfr[j], acc[i][j]);
  }

  __syncthreads();
  for (int w = 0; w < 4; ++w) {
    if (wid == w) {
#pragma unroll
      for (int fm = 0; fm < 4; ++fm)
#pragma unroll
        for (int fn = 0; fn < 4; ++fn)
#pragma unroll
          for (int r = 0; r < 4; ++r) {
            int d = fm * 16 + l4 * 4 + r;
            int e = fn * 16 + l15;
            if (w == 0) red[d * 64 + e] = acc[fm][fn][r];
            else        red[d * 64 + e] += acc[fm][fn][r];
          }
    }
    __syncthreads();
  }
  float* dst = ctxpart + ((size_t)bh * 8 + chunk) * 4096;
#pragma unroll
  for (int i = 0; i < 4; ++i) {
    int q = tid + i * 256;
    *(float4*)&dst[q * 4] = *(const float4*)&red[q * 4];
  }
}

// ---------------- K3: reduce partials, /S, then Mt[b][dcol][h*64+d] ----------------
__global__ __launch_bounds__(256) void k_mt(const float* __restrict__ ctxpart,
                                            const float* __restrict__ S,
                                            const float* __restrict__ w_out,
                                            bf16_t* __restrict__ Mt) {
  __shared__ float cs[4096];
  const int tid = threadIdx.x;
  const int bh = blockIdx.x;
  const int b = bh >> 3, h = bh & 7;
#pragma unroll
  for (int i = 0; i < 16; ++i) {
    int idx = tid + i * 256;
    float s = 0.f;
#pragma unroll
    for (int p = 0; p < 8; ++p) s += ctxpart[((size_t)bh * 8 + p) * 4096 + idx];
    cs[idx] = s / S[b * 512 + h * 64 + (idx >> 6)];
  }
  __syncthreads();
  for (int half = 0; half < 2; ++half) {
    const int dcol = half * 256 + tid;
    float a[64];
#pragma unroll
    for (int d = 0; d < 64; ++d) a[d] = 0.f;
    for (int e = 0; e < 64; ++e) {
      float we = w_out[(size_t)dcol * 512 + h * 64 + e];
#pragma unroll
      for (int d = 0; d < 64; ++d) a[d] += cs[d * 64 + e] * we;
    }
    bf16_t* dst = Mt + ((size_t)b * 512 + dcol) * 512 + h * 64;
#pragma unroll
    for (int g = 0; g < 8; ++g) {
      bf16x8 o;
#pragma unroll
      for (int j = 0; j < 8; ++j) o[j] = (bf16_t)a[g * 8 + j];
      *(bf16x8*)&dst[g * 8] = o;
    }
  }
}

// ---------------- K4: out = LN(qs[b] @ Mt[b]) fused, pipelined, XCD swizzle (batch == xcd) ----------------
__global__ __launch_bounds__(512, 2) void k_out(const bf16_t* __restrict__ qs,
                                                const bf16_t* __restrict__ Mt,
                                                const float* __restrict__ gamma,
                                                float* __restrict__ out) {
  __shared__ __align__(16) bf16_t As[2][128 * 64];  // 2 x 16 KB
  __shared__ __align__(16) bf16_t Bs[512 * 64];     // 64 KB
  __shared__ float redS[128 * 4];
  __shared__ float redQ[128 * 4];
  const int tid = threadIdx.x;
  const int lane = tid & 63;
  const int w = tid >> 6;
  const int wr = w >> 2, wc = w & 3;
  const int l15 = lane & 15, l4 = lane >> 4;
  const int bid = blockIdx.x;
  const int sbid = (bid & 7) * 32 + (bid >> 3);
  const int m0 = sbid * 128;
  const bf16_t* Bp = Mt + (size_t)(sbid >> 5) * 512 * 512;

  int aR[2], aU[2];
#pragma unroll
  for (int i = 0; i < 2; ++i) {
    int s = tid + i * 512;
    aR[i] = s >> 3;
    aU[i] = ((s & 7) ^ (aR[i] & 7)) << 3;
  }
  int bR[8], bU[8];
#pragma unroll
  for (int i = 0; i < 8; ++i) {
    int s = tid + i * 512;
    bR[i] = s >> 3;
    bU[i] = ((s & 7) ^ (bR[i] & 7)) << 3;
  }

  floatx4 acc[4][8];
#pragma unroll
  for (int i = 0; i < 4; ++i)
#pragma unroll
    for (int j = 0; j < 8; ++j) acc[i][j] = (floatx4){0.f, 0.f, 0.f, 0.f};

  bf16x8 breg[8];
#pragma unroll
  for (int i = 0; i < 2; ++i)
    gll16(qs + (size_t)(m0 + aR[i]) * 512 + aU[i], &As[0][(tid + i * 512) * 8]);
#pragma unroll
  for (int i = 0; i < 8; ++i)
    breg[i] = *(const bf16x8*)(Bp + (size_t)bR[i] * 512 + bU[i]);
  asm volatile("s_waitcnt vmcnt(0)" ::: "memory");
#pragma unroll
  for (int i = 0; i < 8; ++i)
    *(bf16x8*)(&Bs[(tid + i * 512) * 8]) = breg[i];
  asm volatile("s_waitcnt lgkmcnt(0)" ::: "memory");
  __builtin_amdgcn_s_barrier();

  for (int t = 0; t < 8; ++t) {
    const int cur = t & 1;
    if (t < 7) {
      const int kt = (t + 1) * 64;
#pragma unroll
      for (int i = 0; i < 2; ++i)
        gll16(qs + (size_t)(m0 + aR[i]) * 512 + kt + aU[i], &As[cur ^ 1][(tid + i * 512) * 8]);
#pragma unroll
      for (int i = 0; i < 8; ++i)
        breg[i] = *(const bf16x8*)(Bp + (size_t)bR[i] * 512 + kt + bU[i]);
    }
    __builtin_amdgcn_s_setprio(1);
#pragma unroll
    for (int kk = 0; kk < 2; ++kk) {
      bf16x8 af[4], bfr[8];
#pragma unroll
      for (int f = 0; f < 4; ++f) {
        int ar = wr * 64 + f * 16 + l15;
        int ua = (kk * 4 + l4) ^ (ar & 7);
        af[f] = *(const bf16x8*)(&As[cur][ar * 64 + ua * 8]);
      }
#pragma unroll
      for (int f = 0; f < 8; ++f) {
        int br = wc * 128 + f * 16 + l15;
        int ub = (kk * 4 + l4) ^ (br & 7);
        bfr[f] = *(const bf16x8*)(&Bs[br * 64 + ub * 8]);
      }
#pragma unroll
      for (int i = 0; i < 4; ++i)
#pragma unroll
        for (int j = 0; j < 8; ++j)
          acc[i][j] = mfma_bf16(af[i], bfr[j], acc[i][j]);
    }
    __builtin_amdgcn_s_setprio(0);
    __builtin_amdgcn_sched_barrier(0);
    __builtin_amdgcn_s_barrier();
    if (t < 7) {
      asm volatile("s_waitcnt vmcnt(0)" ::: "memory");
#pragma unroll
      for (int i = 0; i < 8; ++i)
        *(bf16x8*)(&Bs[(tid + i * 512) * 8]) = breg[i];
      asm volatile("s_waitcnt lgkmcnt(0)" ::: "memory");
      __builtin_amdgcn_s_barrier();
    }
  }

#pragma unroll
  for (int fm = 0; fm < 4; ++fm) {
#pragma unroll
    for (int r = 0; r < 4; ++r) {
      float s = 0.f, q = 0.f;
#pragma unroll
      for (int fn = 0; fn < 8; ++fn) {
        float v = acc[fm][fn][r];
        s += v; q += v * v;
      }
      s += __shfl_xor(s, 1); q += __shfl_xor(q, 1);
      s += __shfl_xor(s, 2); q += __shfl_xor(q, 2);
      s += __shfl_xor(s, 4); q += __shfl_xor(q, 4);
      s += __shfl_xor(s, 8); q += __shfl_xor(q, 8);
      if (l15 == 0) {
        int rl = wr * 64 + fm * 16 + l4 * 4 + r;
        redS[rl * 4 + wc] = s;
        redQ[rl * 4 + wc] = q;
      }
    }
  }
  __syncthreads();
  float gm[8];
#pragma unroll
  for (int fn = 0; fn < 8; ++fn) gm[fn] = gamma[wc * 128 + fn * 16 + l15];
#pragma unroll
  for (int fm = 0; fm < 4; ++fm) {
#pragma unroll
    for (int r = 0; r < 4; ++r) {
      int rl = wr * 64 + fm * 16 + l4 * 4 + r;
      float4 sv = *(const float4*)&redS[rl * 4];
      float4 qv = *(const float4*)&redQ[rl * 4];
      float Sr = sv.x + sv.y + sv.z + sv.w;
      float Qr = qv.x + qv.y + qv.z + qv.w;
      float mean = Sr * (1.f / 512.f);
      float var = Qr * (1.f / 512.f) - mean * mean;
      float rstd = rsqrtf(var + 1e-5f);
      float* rowp = out + (size_t)(m0 + rl) * 512 + wc * 128 + l15;
#pragma unroll
      for (int fn = 0; fn < 8; ++fn)
        rowp[fn * 16] = (acc[fm][fn][r] - mean) * rstd * gm[fn];
    }
  }
}

extern "C" void kernel_launch(void* const* d_in, const int* in_sizes, int n_in,
                              void* d_out, int out_size, void* d_ws, size_t ws_size,
                              hipStream_t stream) {
  const float* x     = (const float*)d_in[0];
  const float* w_qkv = (const float*)d_in[1];
  const float* w_out = (const float*)d_in[2];
  const float* gamma = (const float*)d_in[3];
  float* out = (float*)d_out;
  char* ws = (char*)d_ws;

  bf16_t* qs      = (bf16_t*)(ws);                       // 33,554,432
  bf16_t* ek      = (bf16_t*)(ws + 33554432);            // 33,554,432
  bf16_t* vb      = (bf16_t*)(ws + 67108864);            // 33,554,432
  bf16_t* wqkvb   = (bf16_t*)(ws + 100663296);           //  1,572,864
  float*  S       = (float*)(ws + 102236160);            //     16,384 (pre-Xb, no alias)
  bf16_t* Xb      = (bf16_t*)(ws + 102252544);           // 33,554,432 (dead after k_qkv)
  float*  ctxpart = (float*)(ws + 103301120);            //  8,388,608 (alias Xb tail, written AFTER Xb dead)
  bf16_t* Mt      = (bf16_t*)(ws + 111689728);           //  4,194,304 (alias Xb tail)

  k_cvt2<<<8577, 256, 0, stream>>>(w_qkv, wqkvb, x, Xb, S);

  k_qkv<<<768, 512, 0, stream>>>(Xb, wqkvb, qs, ek, vb, S);

  dim3 g2(64, 8);
  k_ctx<<<g2, 256, 0, stream>>>(ek, vb, ctxpart);

  k_mt<<<64, 256, 0, stream>>>(ctxpart, S, w_out, Mt);

  k_out<<<256, 512, 0, stream>>>(qs, Mt, gamma, out);
}

// Round 19
// 190.478 us; speedup vs baseline: 1.0470x; 1.0106x over previous
//
#include <hip/hip_runtime.h>
#include <hip/hip_bf16.h>
#include <stdint.h>
#include <stddef.h>

typedef __bf16 bf16_t;
typedef __bf16 bf16x8 __attribute__((ext_vector_type(8)));
typedef float floatx4 __attribute__((ext_vector_type(4)));

#define DIM 512
#define SEQ 4096
#define BATCH 8

static __device__ __forceinline__ floatx4 mfma_bf16(bf16x8 a, bf16x8 b, floatx4 c) {
  return __builtin_amdgcn_mfma_f32_16x16x32_bf16(a, b, c, 0, 0, 0);
}

typedef __attribute__((address_space(1))) const void* gas_ptr;
typedef __attribute__((address_space(3))) void* las_ptr;
static __device__ __forceinline__ void gll16(const void* g, void* l) {
  __builtin_amdgcn_global_load_lds((gas_ptr)g, (las_ptr)l, 16, 0, 0);
}

// ---------------- K0: fp32->bf16 (w: 0..383, x: 384..8575) + zero S (block 8576) ----------------
__global__ __launch_bounds__(256) void k_cvt2(const float* __restrict__ w, bf16_t* __restrict__ wb,
                                              const float* __restrict__ x, bf16_t* __restrict__ xb,
                                              float* __restrict__ S) {
  int blk = blockIdx.x;
  if (blk == 8576) {
    float4 zv = {0.f, 0.f, 0.f, 0.f};
    ((float4*)S)[threadIdx.x * 4]     = zv;
    ((float4*)S)[threadIdx.x * 4 + 1] = zv;
    ((float4*)S)[threadIdx.x * 4 + 2] = zv;
    ((float4*)S)[threadIdx.x * 4 + 3] = zv;
    return;
  }
  const float* src;
  bf16_t* dst;
  if (blk < 384) { src = w; dst = wb; }
  else           { src = x; dst = xb; blk -= 384; }
  int i = (blk * 256 + threadIdx.x) * 8;
  float4 a = *(const float4*)&src[i];
  float4 b = *(const float4*)&src[i + 4];
  bf16x8 o;
  o[0] = (bf16_t)a.x; o[1] = (bf16_t)a.y; o[2] = (bf16_t)a.z; o[3] = (bf16_t)a.w;
  o[4] = (bf16_t)b.x; o[5] = (bf16_t)b.y; o[6] = (bf16_t)b.z; o[7] = (bf16_t)b.w;
  *(bf16x8*)&dst[i] = o;
}

// ---------------- K1: qkv GEMM, 256x256 tile, 8 waves, BK=64, dbuf + counted vmcnt(8) + XCD swizzle ----------------
// r11/r15-best config (79us, MfmaUtil 26%, FETCH 35MB, 0 conflicts). FROZEN.
__global__ __launch_bounds__(512, 2) void k_qkv(const bf16_t* __restrict__ Xb,
                                                const bf16_t* __restrict__ Wb,
                                                bf16_t* __restrict__ qs,
                                                bf16_t* __restrict__ ek,
                                                bf16_t* __restrict__ vb,
                                                float* __restrict__ S) {
  __shared__ __align__(16) bf16_t As[2][256 * 64];
  __shared__ __align__(16) bf16_t Bs[2][256 * 64];
  const int tid = threadIdx.x;
  const int lane = tid & 63;
  const int w = tid >> 6;
  const int wr = w >> 2, wc = w & 3;
  const int l15 = lane & 15, l4 = lane >> 4;
  const int bid = blockIdx.x;
  const int xcd = bid & 7, local = bid >> 3;
  const int m0 = (xcd * 16 + local / 6) * 256;
  const int n0 = (local % 6) * 256;

  int sr[4], su[4];
#pragma unroll
  for (int i = 0; i < 4; ++i) {
    int s = tid + i * 512;
    sr[i] = s >> 3;
    su[i] = ((s & 7) ^ (sr[i] & 7)) << 3;
  }

  floatx4 acc[8][4];
#pragma unroll
  for (int i = 0; i < 8; ++i)
#pragma unroll
    for (int j = 0; j < 4; ++j) acc[i][j] = (floatx4){0.f, 0.f, 0.f, 0.f};

#pragma unroll
  for (int i = 0; i < 4; ++i) {
    int s = tid + i * 512;
    gll16(Xb + (size_t)(m0 + sr[i]) * DIM + su[i], &As[0][s * 8]);
    gll16(Wb + (size_t)(n0 + sr[i]) * DIM + su[i], &Bs[0][s * 8]);
  }

  for (int t = 0; t < 8; ++t) {
    const int cur = t & 1;
    if (t < 7) {
      const int kt = (t + 1) * 64;
#pragma unroll
      for (int i = 0; i < 4; ++i) {
        int s = tid + i * 512;
        gll16(Xb + (size_t)(m0 + sr[i]) * DIM + kt + su[i], &As[cur ^ 1][s * 8]);
        gll16(Wb + (size_t)(n0 + sr[i]) * DIM + kt + su[i], &Bs[cur ^ 1][s * 8]);
      }
      asm volatile("s_waitcnt vmcnt(8)" ::: "memory");
    } else {
      asm volatile("s_waitcnt vmcnt(0)" ::: "memory");
    }
    __builtin_amdgcn_s_barrier();
    __builtin_amdgcn_sched_barrier(0);
    __builtin_amdgcn_s_setprio(1);
#pragma unroll
    for (int kk = 0; kk < 2; ++kk) {
      bf16x8 af[8], bfr[4];
#pragma unroll
      for (int f = 0; f < 8; ++f) {
        int ar = wr * 128 + f * 16 + l15;
        int ua = (kk * 4 + l4) ^ (ar & 7);
        af[f] = *(const bf16x8*)(&As[cur][ar * 64 + ua * 8]);
      }
#pragma unroll
      for (int f = 0; f < 4; ++f) {
        int br = wc * 64 + f * 16 + l15;
        int ub = (kk * 4 + l4) ^ (br & 7);
        bfr[f] = *(const bf16x8*)(&Bs[cur][br * 64 + ub * 8]);
      }
#pragma unroll
      for (int i = 0; i < 8; ++i)
#pragma unroll
        for (int j = 0; j < 4; ++j)
          acc[i][j] = mfma_bf16(af[i], bfr[j], acc[i][j]);
    }
    __builtin_amdgcn_s_setprio(0);
    __builtin_amdgcn_sched_barrier(0);
    __builtin_amdgcn_s_barrier();
  }

  const int colbase = n0 + wc * 64;
  if (n0 < 512) {
#pragma unroll
    for (int fm = 0; fm < 8; ++fm) {
#pragma unroll
      for (int r = 0; r < 4; ++r) {
        float v0 = acc[fm][0][r], v1 = acc[fm][1][r], v2 = acc[fm][2][r], v3 = acc[fm][3][r];
        float mx = fmaxf(fmaxf(v0, v1), fmaxf(v2, v3));
        mx = fmaxf(mx, __shfl_xor(mx, 1));
        mx = fmaxf(mx, __shfl_xor(mx, 2));
        mx = fmaxf(mx, __shfl_xor(mx, 4));
        mx = fmaxf(mx, __shfl_xor(mx, 8));
        float e0 = __expf(v0 - mx), e1 = __expf(v1 - mx), e2 = __expf(v2 - mx), e3 = __expf(v3 - mx);
        float s = e0 + e1 + e2 + e3;
        s += __shfl_xor(s, 1); s += __shfl_xor(s, 2); s += __shfl_xor(s, 4); s += __shfl_xor(s, 8);
        float inv = 0.125f / s;
        int m = m0 + wr * 128 + fm * 16 + l4 * 4 + r;
        bf16_t* rowp = qs + (size_t)m * DIM + colbase;
        rowp[l15]      = (bf16_t)(e0 * inv);
        rowp[16 + l15] = (bf16_t)(e1 * inv);
        rowp[32 + l15] = (bf16_t)(e2 * inv);
        rowp[48 + l15] = (bf16_t)(e3 * inv);
      }
    }
  } else if (n0 < 1024) {
    const int cb = colbase - 512;
    float c0 = 0.f, c1 = 0.f, c2 = 0.f, c3 = 0.f;
#pragma unroll
    for (int fm = 0; fm < 8; ++fm) {
#pragma unroll
      for (int r = 0; r < 4; ++r) {
        int m = m0 + wr * 128 + fm * 16 + l4 * 4 + r;
        bf16_t* rowp = ek + (size_t)m * DIM + cb;
        float e0 = __expf(acc[fm][0][r]);
        float e1 = __expf(acc[fm][1][r]);
        float e2 = __expf(acc[fm][2][r]);
        float e3 = __expf(acc[fm][3][r]);
        rowp[l15]      = (bf16_t)e0;
        rowp[16 + l15] = (bf16_t)e1;
        rowp[32 + l15] = (bf16_t)e2;
        rowp[48 + l15] = (bf16_t)e3;
        c0 += e0; c1 += e1; c2 += e2; c3 += e3;
      }
    }
    c0 += __shfl_xor(c0, 16); c0 += __shfl_xor(c0, 32);
    c1 += __shfl_xor(c1, 16); c1 += __shfl_xor(c1, 32);
    c2 += __shfl_xor(c2, 16); c2 += __shfl_xor(c2, 32);
    c3 += __shfl_xor(c3, 16); c3 += __shfl_xor(c3, 32);
    if (lane < 16) {
      int b = m0 >> 12;
      atomicAdd(&S[b * 512 + cb + lane],      c0);
      atomicAdd(&S[b * 512 + cb + 16 + lane], c1);
      atomicAdd(&S[b * 512 + cb + 32 + lane], c2);
      atomicAdd(&S[b * 512 + cb + 48 + lane], c3);
    }
  } else {
    const int cb = colbase - 1024;
#pragma unroll
    for (int fm = 0; fm < 8; ++fm) {
#pragma unroll
      for (int r = 0; r < 4; ++r) {
        int m = m0 + wr * 128 + fm * 16 + l4 * 4 + r;
        bf16_t* rowp = vb + (size_t)m * DIM + cb;
        rowp[l15]      = (bf16_t)acc[fm][0][r];
        rowp[16 + l15] = (bf16_t)acc[fm][1][r];
        rowp[32 + l15] = (bf16_t)acc[fm][2][r];
        rowp[48 + l15] = (bf16_t)acc[fm][3][r];
      }
    }
  }
}

// ---------------- K2: ctxpart = ek_chunk^T @ v_chunk — coalesced staging + XOR-swizzled transpose ----------------
#define TP 136
__global__ __launch_bounds__(256) void k_ctx(const bf16_t* __restrict__ ek,
                                             const bf16_t* __restrict__ vb,
                                             float* __restrict__ ctxpart) {
  __shared__ __align__(16) bf16_t ekT[64 * TP];
  __shared__ __align__(16) bf16_t vT[64 * TP];
  __shared__ float red[4096];
  const int tid = threadIdx.x;
  const int lane = tid & 63, wid = tid >> 6;
  const int l15 = lane & 15, l4 = lane >> 4;
  const int bh = blockIdx.x, chunk = blockIdx.y;
  const int b = bh >> 3, h = bh & 7;
  const int base = b * SEQ + chunk * 512;

  floatx4 acc[4][4];
#pragma unroll
  for (int i = 0; i < 4; ++i)
#pragma unroll
    for (int j = 0; j < 4; ++j) acc[i][j] = (floatx4){0.f, 0.f, 0.f, 0.f};

  for (int nt = 0; nt < 4; ++nt) {
    const int n0 = base + nt * 128;
    if (nt) __syncthreads();
#pragma unroll
    for (int i = 0; i < 4; ++i) {
      int q = tid + i * 256;
      int n = q >> 3;
      int u = q & 7;
      bf16x8 vk = *(const bf16x8*)&ek[(size_t)(n0 + n) * DIM + h * 64 + u * 8];
      bf16x8 vv = *(const bf16x8*)&vb[(size_t)(n0 + n) * DIM + h * 64 + u * 8];
      int ncol = n ^ (u << 3);
#pragma unroll
      for (int j = 0; j < 8; ++j) {
        int c = u * 8 + j;
        ekT[c * TP + ncol] = vk[j];
        vT [c * TP + ncol] = vv[j];
      }
    }
    __syncthreads();
    const int nb = wid * 32;
    bf16x8 af[4], bfr[4];
#pragma unroll
    for (int f = 0; f < 4; ++f) {
      int c = f * 16 + l15;
      int colstart = (nb + l4 * 8) ^ (((c >> 3) & 7) << 3);
      af[f]  = *(const bf16x8*)&ekT[c * TP + colstart];
      bfr[f] = *(const bf16x8*)&vT [c * TP + colstart];
    }
#pragma unroll
    for (int i = 0; i < 4; ++i)
#pragma unroll
      for (int j = 0; j < 4; ++j)
        acc[i][j] = mfma_bf16(af[i], bfr[j], acc[i][j]);
  }

  __syncthreads();
  for (int w = 0; w < 4; ++w) {
    if (wid == w) {
#pragma unroll
      for (int fm = 0; fm < 4; ++fm)
#pragma unroll
        for (int fn = 0; fn < 4; ++fn)
#pragma unroll
          for (int r = 0; r < 4; ++r) {
            int d = fm * 16 + l4 * 4 + r;
            int e = fn * 16 + l15;
            if (w == 0) red[d * 64 + e] = acc[fm][fn][r];
            else        red[d * 64 + e] += acc[fm][fn][r];
          }
    }
    __syncthreads();
  }
  float* dst = ctxpart + ((size_t)bh * 8 + chunk) * 4096;
#pragma unroll
  for (int i = 0; i < 4; ++i) {
    int q = tid + i * 256;
    *(float4*)&dst[q * 4] = *(const float4*)&red[q * 4];
  }
}

// ---------------- K3: reduce partials, /S, then Mt[b][dcol][h*64+d] ----------------
__global__ __launch_bounds__(256) void k_mt(const float* __restrict__ ctxpart,
                                            const float* __restrict__ S,
                                            const float* __restrict__ w_out,
                                            bf16_t* __restrict__ Mt) {
  __shared__ float cs[4096];
  const int tid = threadIdx.x;
  const int bh = blockIdx.x;
  const int b = bh >> 3, h = bh & 7;
#pragma unroll
  for (int i = 0; i < 16; ++i) {
    int idx = tid + i * 256;
    float s = 0.f;
#pragma unroll
    for (int p = 0; p < 8; ++p) s += ctxpart[((size_t)bh * 8 + p) * 4096 + idx];
    cs[idx] = s / S[b * 512 + h * 64 + (idx >> 6)];
  }
  __syncthreads();
  for (int half = 0; half < 2; ++half) {
    const int dcol = half * 256 + tid;
    float a[64];
#pragma unroll
    for (int d = 0; d < 64; ++d) a[d] = 0.f;
    for (int e = 0; e < 64; ++e) {
      float we = w_out[(size_t)dcol * 512 + h * 64 + e];
#pragma unroll
      for (int d = 0; d < 64; ++d) a[d] += cs[d * 64 + e] * we;
    }
    bf16_t* dst = Mt + ((size_t)b * 512 + dcol) * 512 + h * 64;
#pragma unroll
    for (int g = 0; g < 8; ++g) {
      bf16x8 o;
#pragma unroll
      for (int j = 0; j < 8; ++j) o[j] = (bf16_t)a[g * 8 + j];
      *(bf16x8*)&dst[g * 8] = o;
    }
  }
}

// ---------------- K4: out = LN(qs[b] @ Mt[b]) fused. 64-row tiles, 256 thr (4 waves), grid 512 = 2 blocks/CU ----------------
// Wave tile 64x128 (acc[4][8], 256-reg class at (256,2)). A+B via gll, serial 2-phase; cross-block TLP overlaps.
// LDS 74 KB <= 80 KB -> 2 blocks/CU (the 1-block version had zero overlap).
__global__ __launch_bounds__(256, 2) void k_out(const bf16_t* __restrict__ qs,
                                                const bf16_t* __restrict__ Mt,
                                                const float* __restrict__ gamma,
                                                float* __restrict__ out) {
  __shared__ __align__(16) bf16_t As[64 * 64];     //  8 KB
  __shared__ __align__(16) bf16_t Bs[512 * 64];    // 64 KB
  __shared__ float redS[64 * 4];                   //  1 KB
  __shared__ float redQ[64 * 4];                   //  1 KB
  const int tid = threadIdx.x;
  const int lane = tid & 63;
  const int wc = tid >> 6;             // 0..3: column band of 128
  const int l15 = lane & 15, l4 = lane >> 4;
  const int bid = blockIdx.x;
  const int sbid = (bid & 7) * 64 + (bid >> 3);    // 512 = 8 xcd x 64; batch = sbid>>6
  const int m0 = sbid * 64;
  const bf16_t* Bp = Mt + (size_t)(sbid >> 6) * 512 * 512;

  // A: 512 slots, 2/thread; B: 4096 slots, 16/thread
  int aR[2], aU[2];
#pragma unroll
  for (int i = 0; i < 2; ++i) {
    int s = tid + i * 256;
    aR[i] = s >> 3;
    aU[i] = ((s & 7) ^ (aR[i] & 7)) << 3;
  }
  int bR[16], bU[16];
#pragma unroll
  for (int i = 0; i < 16; ++i) {
    int s = tid + i * 256;
    bR[i] = s >> 3;
    bU[i] = ((s & 7) ^ (bR[i] & 7)) << 3;
  }

  floatx4 acc[4][8];
#pragma unroll
  for (int i = 0; i < 4; ++i)
#pragma unroll
    for (int j = 0; j < 8; ++j) acc[i][j] = (floatx4){0.f, 0.f, 0.f, 0.f};

  for (int t = 0; t < 8; ++t) {
    const int kt = t * 64;
    if (t) __builtin_amdgcn_s_barrier();   // previous tile's reads done before overwrite
#pragma unroll
    for (int i = 0; i < 2; ++i)
      gll16(qs + (size_t)(m0 + aR[i]) * 512 + kt + aU[i], &As[(tid + i * 256) * 8]);
#pragma unroll
    for (int i = 0; i < 16; ++i)
      gll16(Bp + (size_t)bR[i] * 512 + kt + bU[i], &Bs[(tid + i * 256) * 8]);
    asm volatile("s_waitcnt vmcnt(0)" ::: "memory");
    __builtin_amdgcn_s_barrier();
    __builtin_amdgcn_s_setprio(1);
#pragma unroll
    for (int kk = 0; kk < 2; ++kk) {
      bf16x8 af[4], bfr[8];
#pragma unroll
      for (int f = 0; f < 4; ++f) {
        int ar = f * 16 + l15;
        int ua = (kk * 4 + l4) ^ (ar & 7);
        af[f] = *(const bf16x8*)(&As[ar * 64 + ua * 8]);
      }
#pragma unroll
      for (int f = 0; f < 8; ++f) {
        int br = wc * 128 + f * 16 + l15;
        int ub = (kk * 4 + l4) ^ (br & 7);
        bfr[f] = *(const bf16x8*)(&Bs[br * 64 + ub * 8]);
      }
#pragma unroll
      for (int i = 0; i < 4; ++i)
#pragma unroll
        for (int j = 0; j < 8; ++j)
          acc[i][j] = mfma_bf16(af[i], bfr[j], acc[i][j]);
    }
    __builtin_amdgcn_s_setprio(0);
    __builtin_amdgcn_sched_barrier(0);
  }
  __builtin_amdgcn_s_barrier();

  // fused LayerNorm: rows fm*16 + l4*4 + r (0..63); cols wc*128 + fn*16 + l15
#pragma unroll
  for (int fm = 0; fm < 4; ++fm) {
#pragma unroll
    for (int r = 0; r < 4; ++r) {
      float s = 0.f, q = 0.f;
#pragma unroll
      for (int fn = 0; fn < 8; ++fn) {
        float v = acc[fm][fn][r];
        s += v; q += v * v;
      }
      s += __shfl_xor(s, 1); q += __shfl_xor(q, 1);
      s += __shfl_xor(s, 2); q += __shfl_xor(q, 2);
      s += __shfl_xor(s, 4); q += __shfl_xor(q, 4);
      s += __shfl_xor(s, 8); q += __shfl_xor(q, 8);
      if (l15 == 0) {
        int rl = fm * 16 + l4 * 4 + r;
        redS[rl * 4 + wc] = s;
        redQ[rl * 4 + wc] = q;
      }
    }
  }
  __syncthreads();
  float gm[8];
#pragma unroll
  for (int fn = 0; fn < 8; ++fn) gm[fn] = gamma[wc * 128 + fn * 16 + l15];
#pragma unroll
  for (int fm = 0; fm < 4; ++fm) {
#pragma unroll
    for (int r = 0; r < 4; ++r) {
      int rl = fm * 16 + l4 * 4 + r;
      float4 sv = *(const float4*)&redS[rl * 4];
      float4 qv = *(const float4*)&redQ[rl * 4];
      float Sr = sv.x + sv.y + sv.z + sv.w;
      float Qr = qv.x + qv.y + qv.z + qv.w;
      float mean = Sr * (1.f / 512.f);
      float var = Qr * (1.f / 512.f) - mean * mean;
      float rstd = rsqrtf(var + 1e-5f);
      float* rowp = out + (size_t)(m0 + rl) * 512 + wc * 128 + l15;
#pragma unroll
      for (int fn = 0; fn < 8; ++fn)
        rowp[fn * 16] = (acc[fm][fn][r] - mean) * rstd * gm[fn];
    }
  }
}

extern "C" void kernel_launch(void* const* d_in, const int* in_sizes, int n_in,
                              void* d_out, int out_size, void* d_ws, size_t ws_size,
                              hipStream_t stream) {
  const float* x     = (const float*)d_in[0];
  const float* w_qkv = (const float*)d_in[1];
  const float* w_out = (const float*)d_in[2];
  const float* gamma = (const float*)d_in[3];
  float* out = (float*)d_out;
  char* ws = (char*)d_ws;

  bf16_t* qs      = (bf16_t*)(ws);                       // 33,554,432
  bf16_t* ek      = (bf16_t*)(ws + 33554432);            // 33,554,432
  bf16_t* vb      = (bf16_t*)(ws + 67108864);            // 33,554,432
  bf16_t* wqkvb   = (bf16_t*)(ws + 100663296);           //  1,572,864
  float*  S       = (float*)(ws + 102236160);            //     16,384 (pre-Xb, no alias)
  bf16_t* Xb      = (bf16_t*)(ws + 102252544);           // 33,554,432 (dead after k_qkv)
  float*  ctxpart = (float*)(ws + 103301120);            //  8,388,608 (alias Xb tail, written AFTER Xb dead)
  bf16_t* Mt      = (bf16_t*)(ws + 111689728);           //  4,194,304 (alias Xb tail)

  k_cvt2<<<8577, 256, 0, stream>>>(w_qkv, wqkvb, x, Xb, S);

  k_qkv<<<768, 512, 0, stream>>>(Xb, wqkvb, qs, ek, vb, S);

  dim3 g2(64, 8);
  k_ctx<<<g2, 256, 0, stream>>>(ek, vb, ctxpart);

  k_mt<<<64, 256, 0, stream>>>(ctxpart, S, w_out, Mt);

  k_out<<<512, 256, 0, stream>>>(qs, Mt, gamma, out);
}

// Round 21
// 190.174 us; speedup vs baseline: 1.0486x; 1.0016x over previous
//
#include <hip/hip_runtime.h>
#include <hip/hip_bf16.h>
#include <stdint.h>
#include <stddef.h>

typedef __bf16 bf16_t;
typedef __bf16 bf16x8 __attribute__((ext_vector_type(8)));
typedef float floatx4 __attribute__((ext_vector_type(4)));

#define DIM 512
#define SEQ 4096
#define BATCH 8

static __device__ __forceinline__ floatx4 mfma_bf16(bf16x8 a, bf16x8 b, floatx4 c) {
  return __builtin_amdgcn_mfma_f32_16x16x32_bf16(a, b, c, 0, 0, 0);
}

typedef __attribute__((address_space(1))) const void* gas_ptr;
typedef __attribute__((address_space(3))) void* las_ptr;
static __device__ __forceinline__ void gll16(const void* g, void* l) {
  __builtin_amdgcn_global_load_lds((gas_ptr)g, (las_ptr)l, 16, 0, 0);
}

// ---------------- K0: fp32->bf16 (w: 0..383, x: 384..8575) + zero S (block 8576) ----------------
__global__ __launch_bounds__(256) void k_cvt2(const float* __restrict__ w, bf16_t* __restrict__ wb,
                                              const float* __restrict__ x, bf16_t* __restrict__ xb,
                                              float* __restrict__ S) {
  int blk = blockIdx.x;
  if (blk == 8576) {
    float4 zv = {0.f, 0.f, 0.f, 0.f};
    ((float4*)S)[threadIdx.x * 4]     = zv;
    ((float4*)S)[threadIdx.x * 4 + 1] = zv;
    ((float4*)S)[threadIdx.x * 4 + 2] = zv;
    ((float4*)S)[threadIdx.x * 4 + 3] = zv;
    return;
  }
  const float* src;
  bf16_t* dst;
  if (blk < 384) { src = w; dst = wb; }
  else           { src = x; dst = xb; blk -= 384; }
  int i = (blk * 256 + threadIdx.x) * 8;
  float4 a = *(const float4*)&src[i];
  float4 b = *(const float4*)&src[i + 4];
  bf16x8 o;
  o[0] = (bf16_t)a.x; o[1] = (bf16_t)a.y; o[2] = (bf16_t)a.z; o[3] = (bf16_t)a.w;
  o[4] = (bf16_t)b.x; o[5] = (bf16_t)b.y; o[6] = (bf16_t)b.z; o[7] = (bf16_t)b.w;
  *(bf16x8*)&dst[i] = o;
}

// ---------------- K1: qkv GEMM, 256x256 tile, 8 waves, BK=64, dbuf + counted vmcnt(8) + XCD swizzle ----------------
// r11/r15-best config (79us, MfmaUtil 26%, FETCH 35MB, 0 conflicts). FROZEN.
__global__ __launch_bounds__(512, 2) void k_qkv(const bf16_t* __restrict__ Xb,
                                                const bf16_t* __restrict__ Wb,
                                                bf16_t* __restrict__ qs,
                                                bf16_t* __restrict__ ek,
                                                bf16_t* __restrict__ vb,
                                                float* __restrict__ S) {
  __shared__ __align__(16) bf16_t As[2][256 * 64];
  __shared__ __align__(16) bf16_t Bs[2][256 * 64];
  const int tid = threadIdx.x;
  const int lane = tid & 63;
  const int w = tid >> 6;
  const int wr = w >> 2, wc = w & 3;
  const int l15 = lane & 15, l4 = lane >> 4;
  const int bid = blockIdx.x;
  const int xcd = bid & 7, local = bid >> 3;
  const int m0 = (xcd * 16 + local / 6) * 256;
  const int n0 = (local % 6) * 256;

  int sr[4], su[4];
#pragma unroll
  for (int i = 0; i < 4; ++i) {
    int s = tid + i * 512;
    sr[i] = s >> 3;
    su[i] = ((s & 7) ^ (sr[i] & 7)) << 3;
  }

  floatx4 acc[8][4];
#pragma unroll
  for (int i = 0; i < 8; ++i)
#pragma unroll
    for (int j = 0; j < 4; ++j) acc[i][j] = (floatx4){0.f, 0.f, 0.f, 0.f};

#pragma unroll
  for (int i = 0; i < 4; ++i) {
    int s = tid + i * 512;
    gll16(Xb + (size_t)(m0 + sr[i]) * DIM + su[i], &As[0][s * 8]);
    gll16(Wb + (size_t)(n0 + sr[i]) * DIM + su[i], &Bs[0][s * 8]);
  }

  for (int t = 0; t < 8; ++t) {
    const int cur = t & 1;
    if (t < 7) {
      const int kt = (t + 1) * 64;
#pragma unroll
      for (int i = 0; i < 4; ++i) {
        int s = tid + i * 512;
        gll16(Xb + (size_t)(m0 + sr[i]) * DIM + kt + su[i], &As[cur ^ 1][s * 8]);
        gll16(Wb + (size_t)(n0 + sr[i]) * DIM + kt + su[i], &Bs[cur ^ 1][s * 8]);
      }
      asm volatile("s_waitcnt vmcnt(8)" ::: "memory");
    } else {
      asm volatile("s_waitcnt vmcnt(0)" ::: "memory");
    }
    __builtin_amdgcn_s_barrier();
    __builtin_amdgcn_sched_barrier(0);
    __builtin_amdgcn_s_setprio(1);
#pragma unroll
    for (int kk = 0; kk < 2; ++kk) {
      bf16x8 af[8], bfr[4];
#pragma unroll
      for (int f = 0; f < 8; ++f) {
        int ar = wr * 128 + f * 16 + l15;
        int ua = (kk * 4 + l4) ^ (ar & 7);
        af[f] = *(const bf16x8*)(&As[cur][ar * 64 + ua * 8]);
      }
#pragma unroll
      for (int f = 0; f < 4; ++f) {
        int br = wc * 64 + f * 16 + l15;
        int ub = (kk * 4 + l4) ^ (br & 7);
        bfr[f] = *(const bf16x8*)(&Bs[cur][br * 64 + ub * 8]);
      }
#pragma unroll
      for (int i = 0; i < 8; ++i)
#pragma unroll
        for (int j = 0; j < 4; ++j)
          acc[i][j] = mfma_bf16(af[i], bfr[j], acc[i][j]);
    }
    __builtin_amdgcn_s_setprio(0);
    __builtin_amdgcn_sched_barrier(0);
    __builtin_amdgcn_s_barrier();
  }

  const int colbase = n0 + wc * 64;
  if (n0 < 512) {
#pragma unroll
    for (int fm = 0; fm < 8; ++fm) {
#pragma unroll
      for (int r = 0; r < 4; ++r) {
        float v0 = acc[fm][0][r], v1 = acc[fm][1][r], v2 = acc[fm][2][r], v3 = acc[fm][3][r];
        float mx = fmaxf(fmaxf(v0, v1), fmaxf(v2, v3));
        mx = fmaxf(mx, __shfl_xor(mx, 1));
        mx = fmaxf(mx, __shfl_xor(mx, 2));
        mx = fmaxf(mx, __shfl_xor(mx, 4));
        mx = fmaxf(mx, __shfl_xor(mx, 8));
        float e0 = __expf(v0 - mx), e1 = __expf(v1 - mx), e2 = __expf(v2 - mx), e3 = __expf(v3 - mx);
        float s = e0 + e1 + e2 + e3;
        s += __shfl_xor(s, 1); s += __shfl_xor(s, 2); s += __shfl_xor(s, 4); s += __shfl_xor(s, 8);
        float inv = 0.125f / s;
        int m = m0 + wr * 128 + fm * 16 + l4 * 4 + r;
        bf16_t* rowp = qs + (size_t)m * DIM + colbase;
        rowp[l15]      = (bf16_t)(e0 * inv);
        rowp[16 + l15] = (bf16_t)(e1 * inv);
        rowp[32 + l15] = (bf16_t)(e2 * inv);
        rowp[48 + l15] = (bf16_t)(e3 * inv);
      }
    }
  } else if (n0 < 1024) {
    const int cb = colbase - 512;
    float c0 = 0.f, c1 = 0.f, c2 = 0.f, c3 = 0.f;
#pragma unroll
    for (int fm = 0; fm < 8; ++fm) {
#pragma unroll
      for (int r = 0; r < 4; ++r) {
        int m = m0 + wr * 128 + fm * 16 + l4 * 4 + r;
        bf16_t* rowp = ek + (size_t)m * DIM + cb;
        float e0 = __expf(acc[fm][0][r]);
        float e1 = __expf(acc[fm][1][r]);
        float e2 = __expf(acc[fm][2][r]);
        float e3 = __expf(acc[fm][3][r]);
        rowp[l15]      = (bf16_t)e0;
        rowp[16 + l15] = (bf16_t)e1;
        rowp[32 + l15] = (bf16_t)e2;
        rowp[48 + l15] = (bf16_t)e3;
        c0 += e0; c1 += e1; c2 += e2; c3 += e3;
      }
    }
    c0 += __shfl_xor(c0, 16); c0 += __shfl_xor(c0, 32);
    c1 += __shfl_xor(c1, 16); c1 += __shfl_xor(c1, 32);
    c2 += __shfl_xor(c2, 16); c2 += __shfl_xor(c2, 32);
    c3 += __shfl_xor(c3, 16); c3 += __shfl_xor(c3, 32);
    if (lane < 16) {
      int b = m0 >> 12;
      atomicAdd(&S[b * 512 + cb + lane],      c0);
      atomicAdd(&S[b * 512 + cb + 16 + lane], c1);
      atomicAdd(&S[b * 512 + cb + 32 + lane], c2);
      atomicAdd(&S[b * 512 + cb + 48 + lane], c3);
    }
  } else {
    const int cb = colbase - 1024;
#pragma unroll
    for (int fm = 0; fm < 8; ++fm) {
#pragma unroll
      for (int r = 0; r < 4; ++r) {
        int m = m0 + wr * 128 + fm * 16 + l4 * 4 + r;
        bf16_t* rowp = vb + (size_t)m * DIM + cb;
        rowp[l15]      = (bf16_t)acc[fm][0][r];
        rowp[16 + l15] = (bf16_t)acc[fm][1][r];
        rowp[32 + l15] = (bf16_t)acc[fm][2][r];
        rowp[48 + l15] = (bf16_t)acc[fm][3][r];
      }
    }
  }
}

// ---------------- K2: ctxpart = ek_chunk^T @ v_chunk — coalesced staging + XOR-swizzled transpose (r19 proven) ----------------
#define TP 136
__global__ __launch_bounds__(256) void k_ctx(const bf16_t* __restrict__ ek,
                                             const bf16_t* __restrict__ vb,
                                             float* __restrict__ ctxpart) {
  __shared__ __align__(16) bf16_t ekT[64 * TP];
  __shared__ __align__(16) bf16_t vT[64 * TP];
  __shared__ float red[4096];
  const int tid = threadIdx.x;
  const int lane = tid & 63, wid = tid >> 6;
  const int l15 = lane & 15, l4 = lane >> 4;
  const int bh = blockIdx.x, chunk = blockIdx.y;
  const int b = bh >> 3, h = bh & 7;
  const int base = b * SEQ + chunk * 512;

  floatx4 acc[4][4];
#pragma unroll
  for (int i = 0; i < 4; ++i)
#pragma unroll
    for (int j = 0; j < 4; ++j) acc[i][j] = (floatx4){0.f, 0.f, 0.f, 0.f};

  for (int nt = 0; nt < 4; ++nt) {
    const int n0 = base + nt * 128;
    if (nt) __syncthreads();
#pragma unroll
    for (int i = 0; i < 4; ++i) {
      int q = tid + i * 256;
      int n = q >> 3;
      int u = q & 7;
      bf16x8 vk = *(const bf16x8*)&ek[(size_t)(n0 + n) * DIM + h * 64 + u * 8];
      bf16x8 vv = *(const bf16x8*)&vb[(size_t)(n0 + n) * DIM + h * 64 + u * 8];
      int ncol = n ^ (u << 3);
#pragma unroll
      for (int j = 0; j < 8; ++j) {
        int c = u * 8 + j;
        ekT[c * TP + ncol] = vk[j];
        vT [c * TP + ncol] = vv[j];
      }
    }
    __syncthreads();
    const int nb = wid * 32;
    bf16x8 af[4], bfr[4];
#pragma unroll
    for (int f = 0; f < 4; ++f) {
      int c = f * 16 + l15;
      int colstart = (nb + l4 * 8) ^ (((c >> 3) & 7) << 3);
      af[f]  = *(const bf16x8*)&ekT[c * TP + colstart];
      bfr[f] = *(const bf16x8*)&vT [c * TP + colstart];
    }
#pragma unroll
    for (int i = 0; i < 4; ++i)
#pragma unroll
      for (int j = 0; j < 4; ++j)
        acc[i][j] = mfma_bf16(af[i], bfr[j], acc[i][j]);
  }

  __syncthreads();
  for (int w = 0; w < 4; ++w) {
    if (wid == w) {
#pragma unroll
      for (int fm = 0; fm < 4; ++fm)
#pragma unroll
        for (int fn = 0; fn < 4; ++fn)
#pragma unroll
          for (int r = 0; r < 4; ++r) {
            int d = fm * 16 + l4 * 4 + r;
            int e = fn * 16 + l15;
            if (w == 0) red[d * 64 + e] = acc[fm][fn][r];
            else        red[d * 64 + e] += acc[fm][fn][r];
          }
    }
    __syncthreads();
  }
  float* dst = ctxpart + ((size_t)bh * 8 + chunk) * 4096;
#pragma unroll
  for (int i = 0; i < 4; ++i) {
    int q = tid + i * 256;
    *(float4*)&dst[q * 4] = *(const float4*)&red[q * 4];
  }
}

// ---------------- K3: reduce partials, /S, then Mt[b][dcol][h*64+d] ----------------
__global__ __launch_bounds__(256) void k_mt(const float* __restrict__ ctxpart,
                                            const float* __restrict__ S,
                                            const float* __restrict__ w_out,
                                            bf16_t* __restrict__ Mt) {
  __shared__ float cs[4096];
  const int tid = threadIdx.x;
  const int bh = blockIdx.x;
  const int b = bh >> 3, h = bh & 7;
#pragma unroll
  for (int i = 0; i < 16; ++i) {
    int idx = tid + i * 256;
    float s = 0.f;
#pragma unroll
    for (int p = 0; p < 8; ++p) s += ctxpart[((size_t)bh * 8 + p) * 4096 + idx];
    cs[idx] = s / S[b * 512 + h * 64 + (idx >> 6)];
  }
  __syncthreads();
  for (int half = 0; half < 2; ++half) {
    const int dcol = half * 256 + tid;
    float a[64];
#pragma unroll
    for (int d = 0; d < 64; ++d) a[d] = 0.f;
    for (int e = 0; e < 64; ++e) {
      float we = w_out[(size_t)dcol * 512 + h * 64 + e];
#pragma unroll
      for (int d = 0; d < 64; ++d) a[d] += cs[d * 64 + e] * we;
    }
    bf16_t* dst = Mt + ((size_t)b * 512 + dcol) * 512 + h * 64;
#pragma unroll
    for (int g = 0; g < 8; ++g) {
      bf16x8 o;
#pragma unroll
      for (int j = 0; j < 8; ++j) o[j] = (bf16_t)a[g * 8 + j];
      *(bf16x8*)&dst[g * 8] = o;
    }
  }
}

// ---------------- K4: out = LN(qs[b] @ Mt[b]) fused. 64-row tiles, 256 thr, grid 512 = 2 blocks/CU ----------------
__global__ __launch_bounds__(256, 2) void k_out(const bf16_t* __restrict__ qs,
                                                const bf16_t* __restrict__ Mt,
                                                const float* __restrict__ gamma,
                                                float* __restrict__ out) {
  __shared__ __align__(16) bf16_t As[64 * 64];
  __shared__ __align__(16) bf16_t Bs[512 * 64];
  __shared__ float redS[64 * 4];
  __shared__ float redQ[64 * 4];
  const int tid = threadIdx.x;
  const int lane = tid & 63;
  const int wc = tid >> 6;
  const int l15 = lane & 15, l4 = lane >> 4;
  const int bid = blockIdx.x;
  const int sbid = (bid & 7) * 64 + (bid >> 3);
  const int m0 = sbid * 64;
  const bf16_t* Bp = Mt + (size_t)(sbid >> 6) * 512 * 512;

  int aR[2], aU[2];
#pragma unroll
  for (int i = 0; i < 2; ++i) {
    int s = tid + i * 256;
    aR[i] = s >> 3;
    aU[i] = ((s & 7) ^ (aR[i] & 7)) << 3;
  }
  int bR[16], bU[16];
#pragma unroll
  for (int i = 0; i < 16; ++i) {
    int s = tid + i * 256;
    bR[i] = s >> 3;
    bU[i] = ((s & 7) ^ (bR[i] & 7)) << 3;
  }

  floatx4 acc[4][8];
#pragma unroll
  for (int i = 0; i < 4; ++i)
#pragma unroll
    for (int j = 0; j < 8; ++j) acc[i][j] = (floatx4){0.f, 0.f, 0.f, 0.f};

  for (int t = 0; t < 8; ++t) {
    const int kt = t * 64;
    if (t) __builtin_amdgcn_s_barrier();
#pragma unroll
    for (int i = 0; i < 2; ++i)
      gll16(qs + (size_t)(m0 + aR[i]) * 512 + kt + aU[i], &As[(tid + i * 256) * 8]);
#pragma unroll
    for (int i = 0; i < 16; ++i)
      gll16(Bp + (size_t)bR[i] * 512 + kt + bU[i], &Bs[(tid + i * 256) * 8]);
    asm volatile("s_waitcnt vmcnt(0)" ::: "memory");
    __builtin_amdgcn_s_barrier();
    __builtin_amdgcn_s_setprio(1);
#pragma unroll
    for (int kk = 0; kk < 2; ++kk) {
      bf16x8 af[4], bfr[8];
#pragma unroll
      for (int f = 0; f < 4; ++f) {
        int ar = f * 16 + l15;
        int ua = (kk * 4 + l4) ^ (ar & 7);
        af[f] = *(const bf16x8*)(&As[ar * 64 + ua * 8]);
      }
#pragma unroll
      for (int f = 0; f < 8; ++f) {
        int br = wc * 128 + f * 16 + l15;
        int ub = (kk * 4 + l4) ^ (br & 7);
        bfr[f] = *(const bf16x8*)(&Bs[br * 64 + ub * 8]);
      }
#pragma unroll
      for (int i = 0; i < 4; ++i)
#pragma unroll
        for (int j = 0; j < 8; ++j)
          acc[i][j] = mfma_bf16(af[i], bfr[j], acc[i][j]);
    }
    __builtin_amdgcn_s_setprio(0);
    __builtin_amdgcn_sched_barrier(0);
  }
  __builtin_amdgcn_s_barrier();

#pragma unroll
  for (int fm = 0; fm < 4; ++fm) {
#pragma unroll
    for (int r = 0; r < 4; ++r) {
      float s = 0.f, q = 0.f;
#pragma unroll
      for (int fn = 0; fn < 8; ++fn) {
        float v = acc[fm][fn][r];
        s += v; q += v * v;
      }
      s += __shfl_xor(s, 1); q += __shfl_xor(q, 1);
      s += __shfl_xor(s, 2); q += __shfl_xor(q, 2);
      s += __shfl_xor(s, 4); q += __shfl_xor(q, 4);
      s += __shfl_xor(s, 8); q += __shfl_xor(q, 8);
      if (l15 == 0) {
        int rl = fm * 16 + l4 * 4 + r;
        redS[rl * 4 + wc] = s;
        redQ[rl * 4 + wc] = q;
      }
    }
  }
  __syncthreads();
  float gm[8];
#pragma unroll
  for (int fn = 0; fn < 8; ++fn) gm[fn] = gamma[wc * 128 + fn * 16 + l15];
#pragma unroll
  for (int fm = 0; fm < 4; ++fm) {
#pragma unroll
    for (int r = 0; r < 4; ++r) {
      int rl = fm * 16 + l4 * 4 + r;
      float4 sv = *(const float4*)&redS[rl * 4];
      float4 qv = *(const float4*)&redQ[rl * 4];
      float Sr = sv.x + sv.y + sv.z + sv.w;
      float Qr = qv.x + qv.y + qv.z + qv.w;
      float mean = Sr * (1.f / 512.f);
      float var = Qr * (1.f / 512.f) - mean * mean;
      float rstd = rsqrtf(var + 1e-5f);
      float* rowp = out + (size_t)(m0 + rl) * 512 + wc * 128 + l15;
#pragma unroll
      for (int fn = 0; fn < 8; ++fn)
        rowp[fn * 16] = (acc[fm][fn][r] - mean) * rstd * gm[fn];
    }
  }
}

extern "C" void kernel_launch(void* const* d_in, const int* in_sizes, int n_in,
                              void* d_out, int out_size, void* d_ws, size_t ws_size,
                              hipStream_t stream) {
  const float* x     = (const float*)d_in[0];
  const float* w_qkv = (const float*)d_in[1];
  const float* w_out = (const float*)d_in[2];
  const float* gamma = (const float*)d_in[3];
  float* out = (float*)d_out;
  char* ws = (char*)d_ws;

  bf16_t* qs      = (bf16_t*)(ws);                       // 33,554,432
  bf16_t* ek      = (bf16_t*)(ws + 33554432);            // 33,554,432
  bf16_t* vb      = (bf16_t*)(ws + 67108864);            // 33,554,432
  bf16_t* wqkvb   = (bf16_t*)(ws + 100663296);           //  1,572,864
  float*  S       = (float*)(ws + 102236160);            //     16,384 (pre-Xb, no alias)
  bf16_t* Xb      = (bf16_t*)(ws + 102252544);           // 33,554,432 (dead after k_qkv)
  float*  ctxpart = (float*)(ws + 103301120);            //  8,388,608 (alias Xb tail, written AFTER Xb dead)
  bf16_t* Mt      = (bf16_t*)(ws + 111689728);           //  4,194,304 (alias Xb tail)

  k_cvt2<<<8577, 256, 0, stream>>>(w_qkv, wqkvb, x, Xb, S);

  k_qkv<<<768, 512, 0, stream>>>(Xb, wqkvb, qs, ek, vb, S);

  dim3 g2(64, 8);
  k_ctx<<<g2, 256, 0, stream>>>(ek, vb, ctxpart);

  k_mt<<<64, 256, 0, stream>>>(ctxpart, S, w_out, Mt);

  k_out<<<512, 256, 0, stream>>>(qs, Mt, gamma, out);
}